// Round 6
// baseline (220.576 us; speedup 1.0000x reference)
//
#include <hip/hip_runtime.h>

#define D_NODE 32
#define D_EDGE 16
#define D_IN   48
#define D_OUT  32
#define L2_EPS 1e-12f

#define NPB       64           // nodes per bucket
#define BKT_SHIFT 6            // log2(NPB)
#define MAX_NB    4096         // max buckets in fast path
#define CH        8192         // edges per chunk
#define CTH       1024         // threads for chunk kernels
#define EPT       (CH / CTH)   // edges per thread in chunk kernels
#define ATH       256          // k_accum block size (4 lanes/node x 64 nodes)
#define CAP       2048         // edges per k_accum super-tile (csr capacity)
#define KPT       (CAP / ATH)  // meta regs per thread (8)

// ===========================================================================
// Fast path A (permuted-e): e rows are physically permuted into bucket-slot
// order by the scatter (sequential e reads there; k_accum then reads e
// streaming within a 128KB L2-resident window). Meta shrinks to 4B.
// Fast path B (round-5, verified 116us): e gathered randomly in k_accum.
// NO f32 atomics anywhere in fast paths (LDS f32 atomics = 6.6x slower, r4).
// ===========================================================================

// K1: per-chunk LDS histogram -> one global atomicAdd per (chunk,bucket)
__global__ __launch_bounds__(CTH) void k_count(
    const int* __restrict__ dst, int* __restrict__ cnt, int n_edges, int nb)
{
    extern __shared__ int c[];
    for (int i = threadIdx.x; i < nb; i += CTH) c[i] = 0;
    __syncthreads();
    int base = blockIdx.x * CH + threadIdx.x;
    #pragma unroll
    for (int k = 0; k < EPT; ++k) {
        int i = base + k * CTH;
        if (i < n_edges) atomicAdd(&c[dst[i] >> BKT_SHIFT], 1);
    }
    __syncthreads();
    for (int i = threadIdx.x; i < nb; i += CTH)
        if (c[i]) atomicAdd(&cnt[i], c[i]);
}

// K2: single block: exclusive scan of bucket counts -> offsets + cursor copy
__global__ __launch_bounds__(1024) void k_offs2(
    const int* __restrict__ cnt, int* __restrict__ offsets,
    int* __restrict__ cursor, int nb)
{
    __shared__ int s[1024];
    const int PT = MAX_NB / 1024;
    int t = threadIdx.x;
    int tot[PT];
    int ts = 0;
    #pragma unroll
    for (int j = 0; j < PT; ++j) {
        int b = t * PT + j;
        tot[j] = (b < nb) ? cnt[b] : 0;
        ts += tot[j];
    }
    s[t] = ts;
    __syncthreads();
    for (int off = 1; off < 1024; off <<= 1) {
        int u = (t >= off) ? s[t - off] : 0;
        __syncthreads();
        s[t] += u;
        __syncthreads();
    }
    if (t == 1023) offsets[nb] = s[1023];
    int run = s[t] - ts;
    #pragma unroll
    for (int j = 0; j < PT; ++j) {
        int b = t * PT + j;
        if (b < nb) { offsets[b] = run; cursor[b] = run; run += tot[j]; }
    }
}

// K3a (tier A): fused hist + run-reservation + rank + write meta1 (4B) AND
// permuted e rows (ep[slot] = e[i]). e reads are SEQUENTIAL/coalesced here
// (i is the chunk loop variable); ep writes land in ~320B bucket-run groups.
__global__ __launch_bounds__(CTH) void k_scatter_p(
    const int* __restrict__ dst, const int* __restrict__ src,
    int* __restrict__ cursor, int* __restrict__ meta1,
    float4* __restrict__ ep, const float4* __restrict__ e4,
    int n_edges, int nb)
{
    extern __shared__ int sm[];
    int* lhist = sm;
    int* lbase = sm + nb;
    int* lrank = sm + 2 * nb;
    for (int i = threadIdx.x; i < nb; i += CTH) { lhist[i] = 0; lrank[i] = 0; }
    __syncthreads();
    int base = blockIdx.x * CH + threadIdx.x;
    int d[EPT];
    #pragma unroll
    for (int k = 0; k < EPT; ++k) {
        int i = base + k * CTH;
        if (i < n_edges) {
            d[k] = dst[i];
            atomicAdd(&lhist[d[k] >> BKT_SHIFT], 1);
        }
    }
    __syncthreads();
    for (int i = threadIdx.x; i < nb; i += CTH)
        if (lhist[i]) lbase[i] = atomicAdd(&cursor[i], lhist[i]);
    __syncthreads();
    #pragma unroll
    for (int k = 0; k < EPT; ++k) {
        int i = base + k * CTH;
        if (i < n_edges) {
            int bkt = d[k] >> BKT_SHIFT;
            int r = atomicAdd(&lrank[bkt], 1);
            int slot = lbase[bkt] + r;
            meta1[slot] = src[i] | ((d[k] & (NPB - 1)) << 20);
            const float4* er = e4 + (size_t)i * 4;
            float4 v0 = er[0], v1 = er[1], v2 = er[2], v3 = er[3];
            float4* wp = ep + (size_t)slot * 4;
            wp[0] = v0; wp[1] = v1; wp[2] = v2; wp[3] = v3;
        }
    }
}

// K3b (tier B, round-5 verified): meta2 int2{src|dl<<20, eid}, no e copy.
__global__ __launch_bounds__(CTH) void k_scatter_g(
    const int* __restrict__ dst, const int* __restrict__ src,
    int* __restrict__ cursor, int2* __restrict__ meta2, int n_edges, int nb)
{
    extern __shared__ int sm[];
    int* lhist = sm;
    int* lbase = sm + nb;
    int* lrank = sm + 2 * nb;
    for (int i = threadIdx.x; i < nb; i += CTH) { lhist[i] = 0; lrank[i] = 0; }
    __syncthreads();
    int base = blockIdx.x * CH + threadIdx.x;
    int d[EPT];
    #pragma unroll
    for (int k = 0; k < EPT; ++k) {
        int i = base + k * CTH;
        if (i < n_edges) {
            d[k] = dst[i];
            atomicAdd(&lhist[d[k] >> BKT_SHIFT], 1);
        }
    }
    __syncthreads();
    for (int i = threadIdx.x; i < nb; i += CTH)
        if (lhist[i]) lbase[i] = atomicAdd(&cursor[i], lhist[i]);
    __syncthreads();
    #pragma unroll
    for (int k = 0; k < EPT; ++k) {
        int i = base + k * CTH;
        if (i < n_edges) {
            int bkt = d[k] >> BKT_SHIFT;
            int r = atomicAdd(&lrank[bkt], 1);
            meta2[lbase[bkt] + r] =
                make_int2(src[i] | ((d[k] & (NPB - 1)) << 20), i);
        }
    }
}

// K4a (tier A): one 256-thread block per bucket (64 nodes, 4 lanes/node).
// Phases per CAP=2048 super-tile: meta1 -> 8 int regs + hist; wave0 scan;
// rank -> csr {src, tile-slot}; WALK: h 2x float4 (L3-hot gather) +
// ep[t0+slot] float4 (L2-resident 128KB window, HBM-sequential).
// csr aliased by mrow for the tail: mean -> affine -> l2norm.
__global__ __launch_bounds__(ATH, 8) void k_accum_p(
    const float* __restrict__ h, const float4* __restrict__ ep,
    const float* __restrict__ W, const float* __restrict__ b,
    const int* __restrict__ offsets, const int* __restrict__ meta1,
    float* __restrict__ out, int n_nodes)
{
    __shared__ float Ws[D_IN * D_OUT];
    __shared__ float bs[D_OUT];
    __shared__ int2 csr[CAP];
    __shared__ int cnt[NPB], cnt2[NPB], offs[NPB];

    for (int i = threadIdx.x; i < D_IN * D_OUT; i += ATH) Ws[i] = W[i];
    if (threadIdx.x < D_OUT) bs[threadIdx.x] = b[threadIdx.x];
    if (threadIdx.x < NPB) { cnt[threadIdx.x] = 0; cnt2[threadIdx.x] = 0; }
    __syncthreads();

    int g  = threadIdx.x >> 2;     // node-local 0..63
    int jg = threadIdx.x & 3;      // dim-owner 0..3

    float4 ha0 = make_float4(0.f, 0.f, 0.f, 0.f);
    float4 ha1 = make_float4(0.f, 0.f, 0.f, 0.f);
    float4 ea  = make_float4(0.f, 0.f, 0.f, 0.f);
    float deg = 0.f;

    int b0 = offsets[blockIdx.x], b1 = offsets[blockIdx.x + 1];

    for (int t0 = b0; t0 < b1; t0 += CAP) {
        int tn = min(CAP, b1 - t0);            // >= 1 inside loop

        // A: meta -> regs (coalesced 4B) + hist
        int m[KPT];
        #pragma unroll
        for (int k = 0; k < KPT; ++k) {
            int i = (int)threadIdx.x + k * ATH;
            if (i < tn) {
                m[k] = meta1[t0 + i];
                atomicAdd(&cnt[(m[k] >> 20) & (NPB - 1)], 1);
            }
        }
        __syncthreads();                       // B1: cnt ready

        // B: exclusive scan of 64 counts (wave 0, one per lane)
        if (threadIdx.x < 64) {
            int p = cnt[threadIdx.x];
            int x = p;
            #pragma unroll
            for (int o = 1; o < 64; o <<= 1) {
                int y = __shfl_up(x, o);
                if (threadIdx.x >= o) x += y;
            }
            offs[threadIdx.x] = x - p;
        }
        int myc = cnt[g];                      // cnt stable since B1
        __syncthreads();                       // B2: offs ready

        // C: rank from regs -> csr {src, tile slot}; zero cnt for next pass
        #pragma unroll
        for (int k = 0; k < KPT; ++k) {
            int i = (int)threadIdx.x + k * ATH;
            if (i < tn) {
                int dl = (m[k] >> 20) & (NPB - 1);
                int r = atomicAdd(&cnt2[dl], 1);
                csr[offs[dl] + r] = make_int2(m[k] & 0xFFFFF, i);
            }
        }
        if (threadIdx.x < NPB) cnt[threadIdx.x] = 0;
        deg += (float)myc;
        __syncthreads();                       // B3: csr ready

        // D: WALK — h gather (L3-hot) + ep stream (L2 window)
        int mybase = offs[g];
        #pragma unroll 4
        for (int s = 0; s < myc; ++s) {
            int2 c = csr[mybase + s];          // ds_read_b64, broadcast in group
            const float4* hr = reinterpret_cast<const float4*>(
                h + (size_t)c.x * D_NODE) + 2 * jg;
            float4 h0 = hr[0], h1 = hr[1];
            float4 ev = ep[(size_t)(t0 + c.y) * 4 + jg];
            ha0.x += h0.x; ha0.y += h0.y; ha0.z += h0.z; ha0.w += h0.w;
            ha1.x += h1.x; ha1.y += h1.y; ha1.z += h1.z; ha1.w += h1.w;
            ea.x  += ev.x; ea.y  += ev.y; ea.z  += ev.z; ea.w  += ev.w;
        }
        if (threadIdx.x < NPB) cnt2[threadIdx.x] = 0;
        __syncthreads();                       // B4: csr/cnt/cnt2 reusable
    }

    // csr dead now: alias mrow over it (64*49*4B = 12.5KB <= 16.4KB)
    float (*mrow)[D_IN + 1] = reinterpret_cast<float (*)[D_IN + 1]>(csr);

    int node = blockIdx.x * NPB + g;
    if (node < n_nodes) {
        float inv = 1.f / (deg + 1.f);
        const float4* hs = reinterpret_cast<const float4*>(
            h + (size_t)node * D_NODE) + 2 * jg;
        float4 s0 = hs[0], s1 = hs[1];
        mrow[g][8 * jg + 0] = (ha0.x + s0.x) * inv;
        mrow[g][8 * jg + 1] = (ha0.y + s0.y) * inv;
        mrow[g][8 * jg + 2] = (ha0.z + s0.z) * inv;
        mrow[g][8 * jg + 3] = (ha0.w + s0.w) * inv;
        mrow[g][8 * jg + 4] = (ha1.x + s1.x) * inv;
        mrow[g][8 * jg + 5] = (ha1.y + s1.y) * inv;
        mrow[g][8 * jg + 6] = (ha1.z + s1.z) * inv;
        mrow[g][8 * jg + 7] = (ha1.w + s1.w) * inv;
        mrow[g][D_NODE + 4 * jg + 0] = ea.x * inv;
        mrow[g][D_NODE + 4 * jg + 1] = ea.y * inv;
        mrow[g][D_NODE + 4 * jg + 2] = ea.z * inv;
        mrow[g][D_NODE + 4 * jg + 3] = ea.w * inv;
    }
    __syncthreads();
    if (node >= n_nodes) return;

    const float* row = mrow[g];
    float a[8];
    #pragma unroll
    for (int q = 0; q < 8; ++q) a[q] = bs[jg * 8 + q];
    #pragma unroll
    for (int k = 0; k < D_IN; ++k) {
        float mk = row[k];
        const float* w = Ws + k * D_OUT + jg * 8;
        #pragma unroll
        for (int q = 0; q < 8; ++q) a[q] += mk * w[q];
    }
    float sq = 0.f;
    #pragma unroll
    for (int q = 0; q < 8; ++q) sq += a[q] * a[q];
    sq += __shfl_xor(sq, 1);
    sq += __shfl_xor(sq, 2);
    float r = rsqrtf(fmaxf(sq, L2_EPS));
    float4* o4 = reinterpret_cast<float4*>(out + (size_t)node * D_OUT) + 2 * jg;
    o4[0] = make_float4(a[0] * r, a[1] * r, a[2] * r, a[3] * r);
    o4[1] = make_float4(a[4] * r, a[5] * r, a[6] * r, a[7] * r);
}

// K4b (tier B, round-5 verified): e gathered via eid from meta2.
__global__ __launch_bounds__(ATH, 8) void k_accum_g(
    const float* __restrict__ h, const float4* __restrict__ e4,
    const float* __restrict__ W, const float* __restrict__ b,
    const int* __restrict__ offsets, const int2* __restrict__ meta2,
    float* __restrict__ out, int n_nodes)
{
    __shared__ float Ws[D_IN * D_OUT];
    __shared__ float bs[D_OUT];
    __shared__ int2 csr[CAP];
    __shared__ int cnt[NPB], cnt2[NPB], offs[NPB];

    for (int i = threadIdx.x; i < D_IN * D_OUT; i += ATH) Ws[i] = W[i];
    if (threadIdx.x < D_OUT) bs[threadIdx.x] = b[threadIdx.x];
    if (threadIdx.x < NPB) { cnt[threadIdx.x] = 0; cnt2[threadIdx.x] = 0; }
    __syncthreads();

    int g  = threadIdx.x >> 2;
    int jg = threadIdx.x & 3;

    float4 ha0 = make_float4(0.f, 0.f, 0.f, 0.f);
    float4 ha1 = make_float4(0.f, 0.f, 0.f, 0.f);
    float4 ea  = make_float4(0.f, 0.f, 0.f, 0.f);
    float deg = 0.f;

    int b0 = offsets[blockIdx.x], b1 = offsets[blockIdx.x + 1];

    for (int t0 = b0; t0 < b1; t0 += CAP) {
        int tn = min(CAP, b1 - t0);

        int2 m[KPT];
        #pragma unroll
        for (int k = 0; k < KPT; ++k) {
            int i = (int)threadIdx.x + k * ATH;
            if (i < tn) {
                m[k] = meta2[t0 + i];
                atomicAdd(&cnt[(m[k].x >> 20) & (NPB - 1)], 1);
            }
        }
        __syncthreads();

        if (threadIdx.x < 64) {
            int p = cnt[threadIdx.x];
            int x = p;
            #pragma unroll
            for (int o = 1; o < 64; o <<= 1) {
                int y = __shfl_up(x, o);
                if (threadIdx.x >= o) x += y;
            }
            offs[threadIdx.x] = x - p;
        }
        int myc = cnt[g];
        __syncthreads();

        #pragma unroll
        for (int k = 0; k < KPT; ++k) {
            int i = (int)threadIdx.x + k * ATH;
            if (i < tn) {
                int dl = (m[k].x >> 20) & (NPB - 1);
                int r = atomicAdd(&cnt2[dl], 1);
                csr[offs[dl] + r] = make_int2(m[k].x & 0xFFFFF, m[k].y);
            }
        }
        if (threadIdx.x < NPB) cnt[threadIdx.x] = 0;
        deg += (float)myc;
        __syncthreads();

        int mybase = offs[g];
        #pragma unroll 4
        for (int s = 0; s < myc; ++s) {
            int2 c = csr[mybase + s];
            const float4* hr = reinterpret_cast<const float4*>(
                h + (size_t)c.x * D_NODE) + 2 * jg;
            float4 h0 = hr[0], h1 = hr[1];
            float4 ev = e4[(size_t)c.y * 4 + jg];
            ha0.x += h0.x; ha0.y += h0.y; ha0.z += h0.z; ha0.w += h0.w;
            ha1.x += h1.x; ha1.y += h1.y; ha1.z += h1.z; ha1.w += h1.w;
            ea.x  += ev.x; ea.y  += ev.y; ea.z  += ev.z; ea.w  += ev.w;
        }
        if (threadIdx.x < NPB) cnt2[threadIdx.x] = 0;
        __syncthreads();
    }

    float (*mrow)[D_IN + 1] = reinterpret_cast<float (*)[D_IN + 1]>(csr);

    int node = blockIdx.x * NPB + g;
    if (node < n_nodes) {
        float inv = 1.f / (deg + 1.f);
        const float4* hs = reinterpret_cast<const float4*>(
            h + (size_t)node * D_NODE) + 2 * jg;
        float4 s0 = hs[0], s1 = hs[1];
        mrow[g][8 * jg + 0] = (ha0.x + s0.x) * inv;
        mrow[g][8 * jg + 1] = (ha0.y + s0.y) * inv;
        mrow[g][8 * jg + 2] = (ha0.z + s0.z) * inv;
        mrow[g][8 * jg + 3] = (ha0.w + s0.w) * inv;
        mrow[g][8 * jg + 4] = (ha1.x + s1.x) * inv;
        mrow[g][8 * jg + 5] = (ha1.y + s1.y) * inv;
        mrow[g][8 * jg + 6] = (ha1.z + s1.z) * inv;
        mrow[g][8 * jg + 7] = (ha1.w + s1.w) * inv;
        mrow[g][D_NODE + 4 * jg + 0] = ea.x * inv;
        mrow[g][D_NODE + 4 * jg + 1] = ea.y * inv;
        mrow[g][D_NODE + 4 * jg + 2] = ea.z * inv;
        mrow[g][D_NODE + 4 * jg + 3] = ea.w * inv;
    }
    __syncthreads();
    if (node >= n_nodes) return;

    const float* row = mrow[g];
    float a[8];
    #pragma unroll
    for (int q = 0; q < 8; ++q) a[q] = bs[jg * 8 + q];
    #pragma unroll
    for (int k = 0; k < D_IN; ++k) {
        float mk = row[k];
        const float* w = Ws + k * D_OUT + jg * 8;
        #pragma unroll
        for (int q = 0; q < 8; ++q) a[q] += mk * w[q];
    }
    float sq = 0.f;
    #pragma unroll
    for (int q = 0; q < 8; ++q) sq += a[q] * a[q];
    sq += __shfl_xor(sq, 1);
    sq += __shfl_xor(sq, 2);
    float r = rsqrtf(fmaxf(sq, L2_EPS));
    float4* o4 = reinterpret_cast<float4*>(out + (size_t)node * D_OUT) + 2 * jg;
    o4[0] = make_float4(a[0] * r, a[1] * r, a[2] * r, a[3] * r);
    o4[1] = make_float4(a[4] * r, a[5] * r, a[6] * r, a[7] * r);
}

// ===========================================================================
// Fallback path (round-1, verified): global f32 atomics + per-node pass.
// ===========================================================================
__global__ __launch_bounds__(256) void scatter_kernel(
    const float* __restrict__ h, const float* __restrict__ e,
    const int* __restrict__ src, const int* __restrict__ dst,
    float* __restrict__ agg, float* __restrict__ deg, int n_edges)
{
    int tid  = blockIdx.x * blockDim.x + threadIdx.x;
    int edge = tid >> 4;
    int c    = tid & 15;
    if (edge >= n_edges) return;
    int s = src[edge], d = dst[edge];
    float v0 = h[(size_t)s * D_NODE + c];
    float v1 = h[(size_t)s * D_NODE + 16 + c];
    float v2 = e[(size_t)edge * D_EDGE + c];
    float* row = agg + (size_t)d * D_IN;
    atomicAdd(row + c, v0);
    atomicAdd(row + 16 + c, v1);
    atomicAdd(row + 32 + c, v2);
    if (c == 0) atomicAdd(deg + d, 1.0f);
}

__global__ __launch_bounds__(256) void node_kernel(
    const float* __restrict__ h, const float* __restrict__ W, const float* __restrict__ b,
    const float* __restrict__ agg, const float* __restrict__ deg,
    float* __restrict__ out, int n_nodes)
{
    __shared__ float Ws[D_IN * D_OUT];
    __shared__ float bs[D_OUT];
    for (int i = threadIdx.x; i < D_IN * D_OUT; i += blockDim.x) Ws[i] = W[i];
    if (threadIdx.x < D_OUT) bs[threadIdx.x] = b[threadIdx.x];
    __syncthreads();
    int node = blockIdx.x * blockDim.x + threadIdx.x;
    if (node >= n_nodes) return;
    const float4* h4 = reinterpret_cast<const float4*>(h + (size_t)node * D_NODE);
    const float4* a4 = reinterpret_cast<const float4*>(agg + (size_t)node * D_IN);
    float inv = 1.0f / (deg[node] + 1.0f);
    float m[D_IN];
    #pragma unroll
    for (int k = 0; k < D_NODE / 4; ++k) {
        float4 hv = h4[k]; float4 av = a4[k];
        m[4*k+0] = (hv.x + av.x) * inv; m[4*k+1] = (hv.y + av.y) * inv;
        m[4*k+2] = (hv.z + av.z) * inv; m[4*k+3] = (hv.w + av.w) * inv;
    }
    #pragma unroll
    for (int k = D_NODE / 4; k < D_IN / 4; ++k) {
        float4 av = a4[k];
        m[4*k+0] = av.x * inv; m[4*k+1] = av.y * inv;
        m[4*k+2] = av.z * inv; m[4*k+3] = av.w * inv;
    }
    float acc[D_OUT];
    #pragma unroll
    for (int j = 0; j < D_OUT; ++j) acc[j] = bs[j];
    #pragma unroll
    for (int k = 0; k < D_IN; ++k) {
        float mk = m[k];
        #pragma unroll
        for (int j = 0; j < D_OUT; ++j) acc[j] += mk * Ws[k * D_OUT + j];
    }
    float sq = 0.0f;
    #pragma unroll
    for (int j = 0; j < D_OUT; ++j) sq += acc[j] * acc[j];
    float r = rsqrtf(fmaxf(sq, L2_EPS));
    float4* o4 = reinterpret_cast<float4*>(out + (size_t)node * D_OUT);
    #pragma unroll
    for (int j = 0; j < D_OUT / 4; ++j) {
        float4 v;
        v.x = acc[4*j+0] * r; v.y = acc[4*j+1] * r;
        v.z = acc[4*j+2] * r; v.w = acc[4*j+3] * r;
        o4[j] = v;
    }
}

extern "C" void kernel_launch(void* const* d_in, const int* in_sizes, int n_in,
                              void* d_out, int out_size, void* d_ws, size_t ws_size,
                              hipStream_t stream) {
    const float* h   = (const float*)d_in[0];
    const float* e   = (const float*)d_in[1];
    const float* W   = (const float*)d_in[2];
    const float* b   = (const float*)d_in[3];
    const int*   src = (const int*)d_in[4];
    const int*   dst = (const int*)d_in[5];
    float* out = (float*)d_out;

    const int n_nodes = in_sizes[0] / D_NODE;
    const int n_edges = in_sizes[4];

    const int nb = (n_nodes + NPB - 1) / NPB;
    const int nc = (n_edges + CH - 1) / CH;

    // common header (int units): cnt[nb] | offsets[nb+1] | cursor[nb]
    size_t o_cnt     = 0;
    size_t o_offsets = o_cnt + nb;
    size_t o_cursor  = o_offsets + nb + 1;
    size_t o_hdr_end = o_cursor + nb;

    // tier A: meta1[E] | pad to 16B | ep[E*16 floats]
    size_t o_meta1 = o_hdr_end;
    size_t o_ep    = (o_meta1 + (size_t)n_edges + 3) & ~(size_t)3;
    size_t need_A  = (o_ep + (size_t)n_edges * 16) * sizeof(int);

    // tier B: meta2 int2[E]
    size_t o_meta2 = (o_hdr_end + 1) & ~(size_t)1;
    size_t need_B  = (o_meta2 + (size_t)n_edges * 2) * sizeof(int);

    bool ok_common = (nb <= MAX_NB) && (n_nodes < (1 << 20)) && (n_edges > 0);

    if (ok_common && need_A <= ws_size) {
        int* ws_i    = (int*)d_ws;
        int* cnt     = ws_i + o_cnt;
        int* offsets = ws_i + o_offsets;
        int* cursor  = ws_i + o_cursor;
        int* meta1   = ws_i + o_meta1;
        float4* ep   = (float4*)(ws_i + o_ep);

        hipMemsetAsync(cnt, 0, (size_t)nb * sizeof(int), stream);
        k_count<<<nc, CTH, (size_t)nb * sizeof(int), stream>>>(
            dst, cnt, n_edges, nb);
        k_offs2<<<1, 1024, 0, stream>>>(cnt, offsets, cursor, nb);
        k_scatter_p<<<nc, CTH, (size_t)3 * nb * sizeof(int), stream>>>(
            dst, src, cursor, meta1, ep, (const float4*)e, n_edges, nb);
        k_accum_p<<<nb, ATH, 0, stream>>>(
            h, (const float4*)ep, W, b, offsets, meta1, out, n_nodes);
    } else if (ok_common && need_B <= ws_size) {
        int* ws_i    = (int*)d_ws;
        int* cnt     = ws_i + o_cnt;
        int* offsets = ws_i + o_offsets;
        int* cursor  = ws_i + o_cursor;
        int2* meta2  = (int2*)(ws_i + o_meta2);

        hipMemsetAsync(cnt, 0, (size_t)nb * sizeof(int), stream);
        k_count<<<nc, CTH, (size_t)nb * sizeof(int), stream>>>(
            dst, cnt, n_edges, nb);
        k_offs2<<<1, 1024, 0, stream>>>(cnt, offsets, cursor, nb);
        k_scatter_g<<<nc, CTH, (size_t)3 * nb * sizeof(int), stream>>>(
            dst, src, cursor, meta2, n_edges, nb);
        k_accum_g<<<nb, ATH, 0, stream>>>(
            h, (const float4*)e, W, b, offsets, meta2, out, n_nodes);
    } else {
        float* agg = (float*)d_ws;
        float* deg = agg + (size_t)n_nodes * D_IN;
        hipMemsetAsync(d_ws, 0, (size_t)n_nodes * (D_IN + 1) * sizeof(float), stream);
        long long threads = (long long)n_edges * 16;
        scatter_kernel<<<(int)((threads + 255) / 256), 256, 0, stream>>>(h, e, src, dst, agg, deg, n_edges);
        node_kernel<<<(n_nodes + 255) / 256, 256, 0, stream>>>(h, W, b, agg, deg, out, n_nodes);
    }
}

// Round 7
// 133.207 us; speedup vs baseline: 1.6559x; 1.6559x over previous
//
#include <hip/hip_runtime.h>

#define D_NODE 32
#define D_EDGE 16
#define D_IN   48
#define D_OUT  32
#define L2_EPS 1e-12f

#define NPB       64           // nodes per bucket
#define BKT_SHIFT 6            // log2(NPB)
#define MAX_NB    4096         // max buckets in fast path
#define CH        4096         // edges per chunk (391 blocks at E=1.6M)
#define CTH       512          // threads for chunk kernels (8 waves/block)
#define EPT       (CH / CTH)   // edges per thread in chunk kernels (8)
#define ATH       256          // k_accum block size (4 lanes/node x 64 nodes)
#define CAP       2048         // edges per k_accum super-tile (csr capacity)
#define KPT       (CAP / ATH)  // meta regs per thread (8)

// ===========================================================================
// Fast path (tier B, round-5 verified 116us): bucket-grouped edges; k_accum
// gathers h (L3-hot) and e (random 128B lines) per edge. Measured wall:
// ~5 TB/s aggregate L2-line movement in k_accum. NO f32 atomics anywhere
// (LDS f32 atomics 6.6x slower, r4; permuted-e scatter 1.8 TB/s, r6).
// Front-end grain: 4096-edge chunks, 512 threads -> 391 blocks (vs 196
// 1024-thread blocks in r5: <1 block/CU, ramp/tail waste).
// ===========================================================================

// K1: per-chunk LDS histogram -> one global atomicAdd per (chunk,bucket)
__global__ __launch_bounds__(CTH) void k_count(
    const int* __restrict__ dst, int* __restrict__ cnt, int n_edges, int nb)
{
    extern __shared__ int c[];
    for (int i = threadIdx.x; i < nb; i += CTH) c[i] = 0;
    __syncthreads();
    int base = blockIdx.x * CH + threadIdx.x;
    #pragma unroll
    for (int k = 0; k < EPT; ++k) {
        int i = base + k * CTH;
        if (i < n_edges) atomicAdd(&c[dst[i] >> BKT_SHIFT], 1);
    }
    __syncthreads();
    for (int i = threadIdx.x; i < nb; i += CTH)
        if (c[i]) atomicAdd(&cnt[i], c[i]);
}

// K2: single block: exclusive scan of bucket counts -> offsets + cursor copy
__global__ __launch_bounds__(1024) void k_offs2(
    const int* __restrict__ cnt, int* __restrict__ offsets,
    int* __restrict__ cursor, int nb)
{
    __shared__ int s[1024];
    const int PT = MAX_NB / 1024;
    int t = threadIdx.x;
    int tot[PT];
    int ts = 0;
    #pragma unroll
    for (int j = 0; j < PT; ++j) {
        int b = t * PT + j;
        tot[j] = (b < nb) ? cnt[b] : 0;
        ts += tot[j];
    }
    s[t] = ts;
    __syncthreads();
    for (int off = 1; off < 1024; off <<= 1) {
        int u = (t >= off) ? s[t - off] : 0;
        __syncthreads();
        s[t] += u;
        __syncthreads();
    }
    if (t == 1023) offsets[nb] = s[1023];
    int run = s[t] - ts;
    #pragma unroll
    for (int j = 0; j < PT; ++j) {
        int b = t * PT + j;
        if (b < nb) { offsets[b] = run; cursor[b] = run; run += tot[j]; }
    }
}

// K3: fused hist + run-reservation (global cursor atomic) + rank + write.
// Reads dst ONCE (cached in regs); writes 8B meta2{src|dl<<20, eid} in
// contiguous per-(chunk,bucket) runs. Slot order nondeterministic — fine.
__global__ __launch_bounds__(CTH) void k_scatter_g(
    const int* __restrict__ dst, const int* __restrict__ src,
    int* __restrict__ cursor, int2* __restrict__ meta2, int n_edges, int nb)
{
    extern __shared__ int sm[];
    int* lhist = sm;
    int* lbase = sm + nb;
    int* lrank = sm + 2 * nb;
    for (int i = threadIdx.x; i < nb; i += CTH) { lhist[i] = 0; lrank[i] = 0; }
    __syncthreads();
    int base = blockIdx.x * CH + threadIdx.x;
    int d[EPT];
    #pragma unroll
    for (int k = 0; k < EPT; ++k) {
        int i = base + k * CTH;
        if (i < n_edges) {
            d[k] = dst[i];
            atomicAdd(&lhist[d[k] >> BKT_SHIFT], 1);
        }
    }
    __syncthreads();
    for (int i = threadIdx.x; i < nb; i += CTH)
        if (lhist[i]) lbase[i] = atomicAdd(&cursor[i], lhist[i]);
    __syncthreads();
    #pragma unroll
    for (int k = 0; k < EPT; ++k) {
        int i = base + k * CTH;
        if (i < n_edges) {
            int bkt = d[k] >> BKT_SHIFT;
            int r = atomicAdd(&lrank[bkt], 1);
            meta2[lbase[bkt] + r] =
                make_int2(src[i] | ((d[k] & (NPB - 1)) << 20), i);
        }
    }
}

// K4: one 256-thread block per bucket (64 nodes, 4 lanes/node).
// Super-tiles of CAP=2048 (avg bucket = 1024 edges -> 1 pass):
//   A: meta2 -> 8 int2 regs (static unroll) + LDS hist (int atomics)
//   B: wave0 exclusive-scans 64 counts (1/lane) -> offs
//   C: rank from regs -> csr {src, eid}; zero cnt for next pass
//   D: WALK: group g walks its contiguous run; per edge: h row 2x float4
//      (L2/L3-hot) + e row float4 at e4[eid*4+jg] (4 lanes = 64B contig).
// csr aliased by mrow for the tail: mean -> affine -> l2norm.
__global__ __launch_bounds__(ATH, 8) void k_accum_g(
    const float* __restrict__ h, const float4* __restrict__ e4,
    const float* __restrict__ W, const float* __restrict__ b,
    const int* __restrict__ offsets, const int2* __restrict__ meta2,
    float* __restrict__ out, int n_nodes)
{
    __shared__ float Ws[D_IN * D_OUT];
    __shared__ float bs[D_OUT];
    __shared__ int2 csr[CAP];
    __shared__ int cnt[NPB], cnt2[NPB], offs[NPB];

    for (int i = threadIdx.x; i < D_IN * D_OUT; i += ATH) Ws[i] = W[i];
    if (threadIdx.x < D_OUT) bs[threadIdx.x] = b[threadIdx.x];
    if (threadIdx.x < NPB) { cnt[threadIdx.x] = 0; cnt2[threadIdx.x] = 0; }
    __syncthreads();

    int g  = threadIdx.x >> 2;     // node-local 0..63
    int jg = threadIdx.x & 3;      // dim-owner 0..3

    float4 ha0 = make_float4(0.f, 0.f, 0.f, 0.f);
    float4 ha1 = make_float4(0.f, 0.f, 0.f, 0.f);
    float4 ea  = make_float4(0.f, 0.f, 0.f, 0.f);
    float deg = 0.f;

    int b0 = offsets[blockIdx.x], b1 = offsets[blockIdx.x + 1];

    for (int t0 = b0; t0 < b1; t0 += CAP) {
        int tn = min(CAP, b1 - t0);            // >= 1 inside loop

        // A: meta -> regs (coalesced) + hist
        int2 m[KPT];
        #pragma unroll
        for (int k = 0; k < KPT; ++k) {
            int i = (int)threadIdx.x + k * ATH;
            if (i < tn) {
                m[k] = meta2[t0 + i];
                atomicAdd(&cnt[(m[k].x >> 20) & (NPB - 1)], 1);
            }
        }
        __syncthreads();                       // B1: cnt ready

        // B: exclusive scan of 64 counts (wave 0, one per lane)
        if (threadIdx.x < 64) {
            int p = cnt[threadIdx.x];
            int x = p;
            #pragma unroll
            for (int o = 1; o < 64; o <<= 1) {
                int y = __shfl_up(x, o);
                if (threadIdx.x >= o) x += y;
            }
            offs[threadIdx.x] = x - p;
        }
        int myc = cnt[g];                      // cnt stable since B1
        __syncthreads();                       // B2: offs ready

        // C: rank from regs -> csr {src, eid}; zero cnt for next pass
        #pragma unroll
        for (int k = 0; k < KPT; ++k) {
            int i = (int)threadIdx.x + k * ATH;
            if (i < tn) {
                int dl = (m[k].x >> 20) & (NPB - 1);
                int r = atomicAdd(&cnt2[dl], 1);
                csr[offs[dl] + r] = make_int2(m[k].x & 0xFFFFF, m[k].y);
            }
        }
        if (threadIdx.x < NPB) cnt[threadIdx.x] = 0;
        deg += (float)myc;
        __syncthreads();                       // B3: csr ready

        // D: WALK — h rows + e rows from global (hot), csr from LDS
        int mybase = offs[g];
        #pragma unroll 4
        for (int s = 0; s < myc; ++s) {
            int2 c = csr[mybase + s];          // ds_read_b64, broadcast in group
            const float4* hr = reinterpret_cast<const float4*>(
                h + (size_t)c.x * D_NODE) + 2 * jg;
            float4 h0 = hr[0], h1 = hr[1];
            float4 ev = e4[(size_t)c.y * 4 + jg];
            ha0.x += h0.x; ha0.y += h0.y; ha0.z += h0.z; ha0.w += h0.w;
            ha1.x += h1.x; ha1.y += h1.y; ha1.z += h1.z; ha1.w += h1.w;
            ea.x  += ev.x; ea.y  += ev.y; ea.z  += ev.z; ea.w  += ev.w;
        }
        if (threadIdx.x < NPB) cnt2[threadIdx.x] = 0;
        __syncthreads();                       // B4: csr/cnt/cnt2 reusable
    }

    // csr dead now: alias mrow over it (64*49*4B = 12.5KB <= 16.4KB)
    float (*mrow)[D_IN + 1] = reinterpret_cast<float (*)[D_IN + 1]>(csr);

    int node = blockIdx.x * NPB + g;
    if (node < n_nodes) {
        float inv = 1.f / (deg + 1.f);
        const float4* hs = reinterpret_cast<const float4*>(
            h + (size_t)node * D_NODE) + 2 * jg;
        float4 s0 = hs[0], s1 = hs[1];
        mrow[g][8 * jg + 0] = (ha0.x + s0.x) * inv;
        mrow[g][8 * jg + 1] = (ha0.y + s0.y) * inv;
        mrow[g][8 * jg + 2] = (ha0.z + s0.z) * inv;
        mrow[g][8 * jg + 3] = (ha0.w + s0.w) * inv;
        mrow[g][8 * jg + 4] = (ha1.x + s1.x) * inv;
        mrow[g][8 * jg + 5] = (ha1.y + s1.y) * inv;
        mrow[g][8 * jg + 6] = (ha1.z + s1.z) * inv;
        mrow[g][8 * jg + 7] = (ha1.w + s1.w) * inv;
        mrow[g][D_NODE + 4 * jg + 0] = ea.x * inv;
        mrow[g][D_NODE + 4 * jg + 1] = ea.y * inv;
        mrow[g][D_NODE + 4 * jg + 2] = ea.z * inv;
        mrow[g][D_NODE + 4 * jg + 3] = ea.w * inv;
    }
    __syncthreads();
    if (node >= n_nodes) return;

    // affine: lane jg computes outputs 8*jg .. 8*jg+7 (W broadcast from LDS)
    const float* row = mrow[g];
    float a[8];
    #pragma unroll
    for (int q = 0; q < 8; ++q) a[q] = bs[jg * 8 + q];
    #pragma unroll
    for (int k = 0; k < D_IN; ++k) {
        float mk = row[k];
        const float* w = Ws + k * D_OUT + jg * 8;
        #pragma unroll
        for (int q = 0; q < 8; ++q) a[q] += mk * w[q];
    }
    float sq = 0.f;
    #pragma unroll
    for (int q = 0; q < 8; ++q) sq += a[q] * a[q];
    sq += __shfl_xor(sq, 1);
    sq += __shfl_xor(sq, 2);
    float r = rsqrtf(fmaxf(sq, L2_EPS));
    float4* o4 = reinterpret_cast<float4*>(out + (size_t)node * D_OUT) + 2 * jg;
    o4[0] = make_float4(a[0] * r, a[1] * r, a[2] * r, a[3] * r);
    o4[1] = make_float4(a[4] * r, a[5] * r, a[6] * r, a[7] * r);
}

// ===========================================================================
// Fallback path (round-1, verified): global f32 atomics + per-node pass.
// ===========================================================================
__global__ __launch_bounds__(256) void scatter_kernel(
    const float* __restrict__ h, const float* __restrict__ e,
    const int* __restrict__ src, const int* __restrict__ dst,
    float* __restrict__ agg, float* __restrict__ deg, int n_edges)
{
    int tid  = blockIdx.x * blockDim.x + threadIdx.x;
    int edge = tid >> 4;
    int c    = tid & 15;
    if (edge >= n_edges) return;
    int s = src[edge], d = dst[edge];
    float v0 = h[(size_t)s * D_NODE + c];
    float v1 = h[(size_t)s * D_NODE + 16 + c];
    float v2 = e[(size_t)edge * D_EDGE + c];
    float* row = agg + (size_t)d * D_IN;
    atomicAdd(row + c, v0);
    atomicAdd(row + 16 + c, v1);
    atomicAdd(row + 32 + c, v2);
    if (c == 0) atomicAdd(deg + d, 1.0f);
}

__global__ __launch_bounds__(256) void node_kernel(
    const float* __restrict__ h, const float* __restrict__ W, const float* __restrict__ b,
    const float* __restrict__ agg, const float* __restrict__ deg,
    float* __restrict__ out, int n_nodes)
{
    __shared__ float Ws[D_IN * D_OUT];
    __shared__ float bs[D_OUT];
    for (int i = threadIdx.x; i < D_IN * D_OUT; i += blockDim.x) Ws[i] = W[i];
    if (threadIdx.x < D_OUT) bs[threadIdx.x] = b[threadIdx.x];
    __syncthreads();
    int node = blockIdx.x * blockDim.x + threadIdx.x;
    if (node >= n_nodes) return;
    const float4* h4 = reinterpret_cast<const float4*>(h + (size_t)node * D_NODE);
    const float4* a4 = reinterpret_cast<const float4*>(agg + (size_t)node * D_IN);
    float inv = 1.0f / (deg[node] + 1.0f);
    float m[D_IN];
    #pragma unroll
    for (int k = 0; k < D_NODE / 4; ++k) {
        float4 hv = h4[k]; float4 av = a4[k];
        m[4*k+0] = (hv.x + av.x) * inv; m[4*k+1] = (hv.y + av.y) * inv;
        m[4*k+2] = (hv.z + av.z) * inv; m[4*k+3] = (hv.w + av.w) * inv;
    }
    #pragma unroll
    for (int k = D_NODE / 4; k < D_IN / 4; ++k) {
        float4 av = a4[k];
        m[4*k+0] = av.x * inv; m[4*k+1] = av.y * inv;
        m[4*k+2] = av.z * inv; m[4*k+3] = av.w * inv;
    }
    float acc[D_OUT];
    #pragma unroll
    for (int j = 0; j < D_OUT; ++j) acc[j] = bs[j];
    #pragma unroll
    for (int k = 0; k < D_IN; ++k) {
        float mk = m[k];
        #pragma unroll
        for (int j = 0; j < D_OUT; ++j) acc[j] += mk * Ws[k * D_OUT + j];
    }
    float sq = 0.0f;
    #pragma unroll
    for (int j = 0; j < D_OUT; ++j) sq += acc[j] * acc[j];
    float r = rsqrtf(fmaxf(sq, L2_EPS));
    float4* o4 = reinterpret_cast<float4*>(out + (size_t)node * D_OUT);
    #pragma unroll
    for (int j = 0; j < D_OUT / 4; ++j) {
        float4 v;
        v.x = acc[4*j+0] * r; v.y = acc[4*j+1] * r;
        v.z = acc[4*j+2] * r; v.w = acc[4*j+3] * r;
        o4[j] = v;
    }
}

extern "C" void kernel_launch(void* const* d_in, const int* in_sizes, int n_in,
                              void* d_out, int out_size, void* d_ws, size_t ws_size,
                              hipStream_t stream) {
    const float* h   = (const float*)d_in[0];
    const float* e   = (const float*)d_in[1];
    const float* W   = (const float*)d_in[2];
    const float* b   = (const float*)d_in[3];
    const int*   src = (const int*)d_in[4];
    const int*   dst = (const int*)d_in[5];
    float* out = (float*)d_out;

    const int n_nodes = in_sizes[0] / D_NODE;
    const int n_edges = in_sizes[4];

    const int nb = (n_nodes + NPB - 1) / NPB;
    const int nc = (n_edges + CH - 1) / CH;

    // ws layout (int units): cnt[nb] | offsets[nb+1] | cursor[nb] | pad | meta2 int2[E]
    size_t o_cnt     = 0;
    size_t o_offsets = o_cnt + nb;
    size_t o_cursor  = o_offsets + nb + 1;
    size_t o_meta2   = (o_cursor + (size_t)nb + 1) & ~(size_t)1;
    size_t need      = (o_meta2 + (size_t)n_edges * 2) * sizeof(int);

    if (nb <= MAX_NB && n_nodes < (1 << 20) && need <= ws_size && n_edges > 0) {
        int* ws_i    = (int*)d_ws;
        int* cnt     = ws_i + o_cnt;
        int* offsets = ws_i + o_offsets;
        int* cursor  = ws_i + o_cursor;
        int2* meta2  = (int2*)(ws_i + o_meta2);

        hipMemsetAsync(cnt, 0, (size_t)nb * sizeof(int), stream);
        k_count<<<nc, CTH, (size_t)nb * sizeof(int), stream>>>(
            dst, cnt, n_edges, nb);
        k_offs2<<<1, 1024, 0, stream>>>(cnt, offsets, cursor, nb);
        k_scatter_g<<<nc, CTH, (size_t)3 * nb * sizeof(int), stream>>>(
            dst, src, cursor, meta2, n_edges, nb);
        k_accum_g<<<nb, ATH, 0, stream>>>(
            h, (const float4*)e, W, b, offsets, meta2, out, n_nodes);
    } else {
        float* agg = (float*)d_ws;
        float* deg = agg + (size_t)n_nodes * D_IN;
        hipMemsetAsync(d_ws, 0, (size_t)n_nodes * (D_IN + 1) * sizeof(float), stream);
        long long threads = (long long)n_edges * 16;
        scatter_kernel<<<(int)((threads + 255) / 256), 256, 0, stream>>>(h, e, src, dst, agg, deg, n_edges);
        node_kernel<<<(n_nodes + 255) / 256, 256, 0, stream>>>(h, W, b, agg, deg, out, n_nodes);
    }
}

// Round 8
// 98.947 us; speedup vs baseline: 2.2292x; 1.3462x over previous
//
#include <hip/hip_runtime.h>

#define D_NODE 32
#define D_EDGE 16
#define D_IN   48
#define D_OUT  32
#define L2_EPS 1e-12f

#define NPB       64           // nodes per bucket
#define BKT_SHIFT 6            // log2(NPB)
#define MAX_NB    4096         // max buckets in fast path
#define CH        8192         // edges per chunk (196 blocks at E=1.6M; r7 showed smaller grain HURTS)
#define CTH       1024         // threads for chunk kernels
#define EPT       (CH / CTH)   // edges per thread in chunk kernels (8)
#define ATH       256          // k_accum block size (4 lanes/node x 64 nodes)
#define CAP       2048         // edges per k_accum super-tile (LDS csr capacity)
#define CAPB      4096         // slab capacity per bucket (mean 1024 here; overflow list for the rest)
#define KPT       (CAP / ATH)  // meta regs per thread (8)

// ===========================================================================
// Fast path (tier A, slab): NO counting pre-pass. Bucket b owns slab
// [b*CAPB, b*CAPB+CAPB); k_scatter_c reserves runs via cursor[b] atomics.
// Overflow (adversarial degree skew only) -> global list, drained by a
// correct-but-slow scan in k_accum. Tier B = round-5 exact-offset path
// (verified 116us). NO f32 atomics anywhere in fast paths (r4: LDS f32
// atomics 6.6x slower; r6: permuted-e scatter 1.8 TB/s, net loss).
// k_accum structure byte-identical to the verified r5/r7 one (82us).
// ===========================================================================

// --- tier A -----------------------------------------------------------------

// K-A1: fused hist + slab-run reservation + rank + write meta int2{src|dl, eid}
__global__ __launch_bounds__(CTH) void k_scatter_c(
    const int* __restrict__ dst, const int* __restrict__ src,
    int* __restrict__ cursor, int* __restrict__ ovf_cnt,
    int2* __restrict__ slab, int4* __restrict__ ovf, int n_edges, int nb)
{
    extern __shared__ int sm[];
    int* lhist = sm;
    int* lbase = sm + nb;
    int* lrank = sm + 2 * nb;
    for (int i = threadIdx.x; i < nb; i += CTH) { lhist[i] = 0; lrank[i] = 0; }
    __syncthreads();
    int base = blockIdx.x * CH + threadIdx.x;
    int d[EPT];
    #pragma unroll
    for (int k = 0; k < EPT; ++k) {
        int i = base + k * CTH;
        if (i < n_edges) {
            d[k] = dst[i];
            atomicAdd(&lhist[d[k] >> BKT_SHIFT], 1);
        }
    }
    __syncthreads();
    for (int i = threadIdx.x; i < nb; i += CTH)
        if (lhist[i]) lbase[i] = atomicAdd(&cursor[i], lhist[i]);
    __syncthreads();
    #pragma unroll
    for (int k = 0; k < EPT; ++k) {
        int i = base + k * CTH;
        if (i < n_edges) {
            int bkt = d[k] >> BKT_SHIFT;
            int mv  = src[i] | ((d[k] & (NPB - 1)) << 20);
            int r = atomicAdd(&lrank[bkt], 1);
            int slot = lbase[bkt] + r;
            if (slot < CAPB) {
                slab[(size_t)bkt * CAPB + slot] = make_int2(mv, i);
            } else {
                int o = atomicAdd(ovf_cnt, 1);
                ovf[o] = make_int4(mv, i, bkt, 0);
            }
        }
    }
}

// K-A2: one 256-thread block per bucket (64 nodes, 4 lanes/node).
// Identical phase structure to the verified r5 k_accum (82us): per CAP=2048
// super-tile: meta->regs+hist / wave0 scan / rank->csr / WALK (h 2x float4
// L3-hot gather + e float4, 4 lanes = 64B contig). Edge count from cursor,
// slab base from blockIdx; normally-empty overflow drain before the tail.
// csr aliased by mrow for the tail: mean -> affine -> l2norm.
__global__ __launch_bounds__(ATH, 8) void k_accum_c(
    const float* __restrict__ h, const float4* __restrict__ e4,
    const float* __restrict__ W, const float* __restrict__ b,
    const int* __restrict__ cursor, const int* __restrict__ ovf_cnt,
    const int2* __restrict__ slab, const int4* __restrict__ ovf,
    float* __restrict__ out, int n_nodes)
{
    __shared__ float Ws[D_IN * D_OUT];
    __shared__ float bs[D_OUT];
    __shared__ int2 csr[CAP];
    __shared__ int cnt[NPB], cnt2[NPB], offs[NPB];

    for (int i = threadIdx.x; i < D_IN * D_OUT; i += ATH) Ws[i] = W[i];
    if (threadIdx.x < D_OUT) bs[threadIdx.x] = b[threadIdx.x];
    if (threadIdx.x < NPB) { cnt[threadIdx.x] = 0; cnt2[threadIdx.x] = 0; }
    __syncthreads();

    int g  = threadIdx.x >> 2;     // node-local 0..63
    int jg = threadIdx.x & 3;      // dim-owner 0..3

    float4 ha0 = make_float4(0.f, 0.f, 0.f, 0.f);
    float4 ha1 = make_float4(0.f, 0.f, 0.f, 0.f);
    float4 ea  = make_float4(0.f, 0.f, 0.f, 0.f);
    float deg = 0.f;

    int total = cursor[blockIdx.x];
    int incap = min(total, CAPB);
    const int2* mslab = slab + (size_t)blockIdx.x * CAPB;

    for (int t0 = 0; t0 < incap; t0 += CAP) {
        int tn = min(CAP, incap - t0);         // >= 1 inside loop

        // A: meta -> regs (coalesced) + hist
        int2 m[KPT];
        #pragma unroll
        for (int k = 0; k < KPT; ++k) {
            int i = (int)threadIdx.x + k * ATH;
            if (i < tn) {
                m[k] = mslab[t0 + i];
                atomicAdd(&cnt[(m[k].x >> 20) & (NPB - 1)], 1);
            }
        }
        __syncthreads();                       // B1: cnt ready

        // B: exclusive scan of 64 counts (wave 0, one per lane)
        if (threadIdx.x < 64) {
            int p = cnt[threadIdx.x];
            int x = p;
            #pragma unroll
            for (int o = 1; o < 64; o <<= 1) {
                int y = __shfl_up(x, o);
                if (threadIdx.x >= o) x += y;
            }
            offs[threadIdx.x] = x - p;
        }
        int myc = cnt[g];                      // cnt stable since B1
        __syncthreads();                       // B2: offs ready

        // C: rank from regs -> csr {src, eid}; zero cnt for next pass
        #pragma unroll
        for (int k = 0; k < KPT; ++k) {
            int i = (int)threadIdx.x + k * ATH;
            if (i < tn) {
                int dl = (m[k].x >> 20) & (NPB - 1);
                int r = atomicAdd(&cnt2[dl], 1);
                csr[offs[dl] + r] = make_int2(m[k].x & 0xFFFFF, m[k].y);
            }
        }
        if (threadIdx.x < NPB) cnt[threadIdx.x] = 0;
        deg += (float)myc;
        __syncthreads();                       // B3: csr ready

        // D: WALK — h rows + e rows from global (hot), csr from LDS
        int mybase = offs[g];
        #pragma unroll 4
        for (int s = 0; s < myc; ++s) {
            int2 c = csr[mybase + s];          // ds_read_b64, broadcast in group
            const float4* hr = reinterpret_cast<const float4*>(
                h + (size_t)c.x * D_NODE) + 2 * jg;
            float4 h0 = hr[0], h1 = hr[1];
            float4 ev = e4[(size_t)c.y * 4 + jg];
            ha0.x += h0.x; ha0.y += h0.y; ha0.z += h0.z; ha0.w += h0.w;
            ha1.x += h1.x; ha1.y += h1.y; ha1.z += h1.z; ha1.w += h1.w;
            ea.x  += ev.x; ea.y  += ev.y; ea.z  += ev.z; ea.w  += ev.w;
        }
        if (threadIdx.x < NPB) cnt2[threadIdx.x] = 0;
        __syncthreads();                       // B4: csr/cnt/cnt2 reusable
    }

    // overflow drain (adversarial skew only; novf==0 on sane inputs)
    int novf = ovf_cnt[0];
    for (int i = 0; i < novf; ++i) {
        int4 o = ovf[i];
        if (o.z == (int)blockIdx.x) {
            int dl = (o.x >> 20) & (NPB - 1);
            if (dl == g) {
                const float4* hr = reinterpret_cast<const float4*>(
                    h + (size_t)(o.x & 0xFFFFF) * D_NODE) + 2 * jg;
                float4 h0 = hr[0], h1 = hr[1];
                float4 ev = e4[(size_t)o.y * 4 + jg];
                ha0.x += h0.x; ha0.y += h0.y; ha0.z += h0.z; ha0.w += h0.w;
                ha1.x += h1.x; ha1.y += h1.y; ha1.z += h1.z; ha1.w += h1.w;
                ea.x  += ev.x; ea.y  += ev.y; ea.z  += ev.z; ea.w  += ev.w;
                deg += 1.f;
            }
        }
    }

    // csr dead now: alias mrow over it (64*49*4B = 12.5KB <= 16.4KB)
    float (*mrow)[D_IN + 1] = reinterpret_cast<float (*)[D_IN + 1]>(csr);

    int node = blockIdx.x * NPB + g;
    if (node < n_nodes) {
        float inv = 1.f / (deg + 1.f);
        const float4* hs = reinterpret_cast<const float4*>(
            h + (size_t)node * D_NODE) + 2 * jg;
        float4 s0 = hs[0], s1 = hs[1];
        mrow[g][8 * jg + 0] = (ha0.x + s0.x) * inv;
        mrow[g][8 * jg + 1] = (ha0.y + s0.y) * inv;
        mrow[g][8 * jg + 2] = (ha0.z + s0.z) * inv;
        mrow[g][8 * jg + 3] = (ha0.w + s0.w) * inv;
        mrow[g][8 * jg + 4] = (ha1.x + s1.x) * inv;
        mrow[g][8 * jg + 5] = (ha1.y + s1.y) * inv;
        mrow[g][8 * jg + 6] = (ha1.z + s1.z) * inv;
        mrow[g][8 * jg + 7] = (ha1.w + s1.w) * inv;
        mrow[g][D_NODE + 4 * jg + 0] = ea.x * inv;
        mrow[g][D_NODE + 4 * jg + 1] = ea.y * inv;
        mrow[g][D_NODE + 4 * jg + 2] = ea.z * inv;
        mrow[g][D_NODE + 4 * jg + 3] = ea.w * inv;
    }
    __syncthreads();
    if (node >= n_nodes) return;

    // affine: lane jg computes outputs 8*jg .. 8*jg+7 (W broadcast from LDS)
    const float* row = mrow[g];
    float a[8];
    #pragma unroll
    for (int q = 0; q < 8; ++q) a[q] = bs[jg * 8 + q];
    #pragma unroll
    for (int k = 0; k < D_IN; ++k) {
        float mk = row[k];
        const float* w = Ws + k * D_OUT + jg * 8;
        #pragma unroll
        for (int q = 0; q < 8; ++q) a[q] += mk * w[q];
    }
    float sq = 0.f;
    #pragma unroll
    for (int q = 0; q < 8; ++q) sq += a[q] * a[q];
    sq += __shfl_xor(sq, 1);
    sq += __shfl_xor(sq, 2);
    float r = rsqrtf(fmaxf(sq, L2_EPS));
    float4* o4 = reinterpret_cast<float4*>(out + (size_t)node * D_OUT) + 2 * jg;
    o4[0] = make_float4(a[0] * r, a[1] * r, a[2] * r, a[3] * r);
    o4[1] = make_float4(a[4] * r, a[5] * r, a[6] * r, a[7] * r);
}

// --- tier B (round-5 exact-offset path, verified 116us) ---------------------

__global__ __launch_bounds__(CTH) void k_count(
    const int* __restrict__ dst, int* __restrict__ cnt, int n_edges, int nb)
{
    extern __shared__ int c[];
    for (int i = threadIdx.x; i < nb; i += CTH) c[i] = 0;
    __syncthreads();
    int base = blockIdx.x * CH + threadIdx.x;
    #pragma unroll
    for (int k = 0; k < EPT; ++k) {
        int i = base + k * CTH;
        if (i < n_edges) atomicAdd(&c[dst[i] >> BKT_SHIFT], 1);
    }
    __syncthreads();
    for (int i = threadIdx.x; i < nb; i += CTH)
        if (c[i]) atomicAdd(&cnt[i], c[i]);
}

__global__ __launch_bounds__(1024) void k_offs2(
    const int* __restrict__ cnt, int* __restrict__ offsets,
    int* __restrict__ cursor, int nb)
{
    __shared__ int s[1024];
    const int PT = MAX_NB / 1024;
    int t = threadIdx.x;
    int tot[PT];
    int ts = 0;
    #pragma unroll
    for (int j = 0; j < PT; ++j) {
        int b = t * PT + j;
        tot[j] = (b < nb) ? cnt[b] : 0;
        ts += tot[j];
    }
    s[t] = ts;
    __syncthreads();
    for (int off = 1; off < 1024; off <<= 1) {
        int u = (t >= off) ? s[t - off] : 0;
        __syncthreads();
        s[t] += u;
        __syncthreads();
    }
    if (t == 1023) offsets[nb] = s[1023];
    int run = s[t] - ts;
    #pragma unroll
    for (int j = 0; j < PT; ++j) {
        int b = t * PT + j;
        if (b < nb) { offsets[b] = run; cursor[b] = run; run += tot[j]; }
    }
}

__global__ __launch_bounds__(CTH) void k_scatter_g(
    const int* __restrict__ dst, const int* __restrict__ src,
    int* __restrict__ cursor, int2* __restrict__ meta2, int n_edges, int nb)
{
    extern __shared__ int sm[];
    int* lhist = sm;
    int* lbase = sm + nb;
    int* lrank = sm + 2 * nb;
    for (int i = threadIdx.x; i < nb; i += CTH) { lhist[i] = 0; lrank[i] = 0; }
    __syncthreads();
    int base = blockIdx.x * CH + threadIdx.x;
    int d[EPT];
    #pragma unroll
    for (int k = 0; k < EPT; ++k) {
        int i = base + k * CTH;
        if (i < n_edges) {
            d[k] = dst[i];
            atomicAdd(&lhist[d[k] >> BKT_SHIFT], 1);
        }
    }
    __syncthreads();
    for (int i = threadIdx.x; i < nb; i += CTH)
        if (lhist[i]) lbase[i] = atomicAdd(&cursor[i], lhist[i]);
    __syncthreads();
    #pragma unroll
    for (int k = 0; k < EPT; ++k) {
        int i = base + k * CTH;
        if (i < n_edges) {
            int bkt = d[k] >> BKT_SHIFT;
            int r = atomicAdd(&lrank[bkt], 1);
            meta2[lbase[bkt] + r] =
                make_int2(src[i] | ((d[k] & (NPB - 1)) << 20), i);
        }
    }
}

__global__ __launch_bounds__(ATH, 8) void k_accum_g(
    const float* __restrict__ h, const float4* __restrict__ e4,
    const float* __restrict__ W, const float* __restrict__ b,
    const int* __restrict__ offsets, const int2* __restrict__ meta2,
    float* __restrict__ out, int n_nodes)
{
    __shared__ float Ws[D_IN * D_OUT];
    __shared__ float bs[D_OUT];
    __shared__ int2 csr[CAP];
    __shared__ int cnt[NPB], cnt2[NPB], offs[NPB];

    for (int i = threadIdx.x; i < D_IN * D_OUT; i += ATH) Ws[i] = W[i];
    if (threadIdx.x < D_OUT) bs[threadIdx.x] = b[threadIdx.x];
    if (threadIdx.x < NPB) { cnt[threadIdx.x] = 0; cnt2[threadIdx.x] = 0; }
    __syncthreads();

    int g  = threadIdx.x >> 2;
    int jg = threadIdx.x & 3;

    float4 ha0 = make_float4(0.f, 0.f, 0.f, 0.f);
    float4 ha1 = make_float4(0.f, 0.f, 0.f, 0.f);
    float4 ea  = make_float4(0.f, 0.f, 0.f, 0.f);
    float deg = 0.f;

    int b0 = offsets[blockIdx.x], b1 = offsets[blockIdx.x + 1];

    for (int t0 = b0; t0 < b1; t0 += CAP) {
        int tn = min(CAP, b1 - t0);

        int2 m[KPT];
        #pragma unroll
        for (int k = 0; k < KPT; ++k) {
            int i = (int)threadIdx.x + k * ATH;
            if (i < tn) {
                m[k] = meta2[t0 + i];
                atomicAdd(&cnt[(m[k].x >> 20) & (NPB - 1)], 1);
            }
        }
        __syncthreads();

        if (threadIdx.x < 64) {
            int p = cnt[threadIdx.x];
            int x = p;
            #pragma unroll
            for (int o = 1; o < 64; o <<= 1) {
                int y = __shfl_up(x, o);
                if (threadIdx.x >= o) x += y;
            }
            offs[threadIdx.x] = x - p;
        }
        int myc = cnt[g];
        __syncthreads();

        #pragma unroll
        for (int k = 0; k < KPT; ++k) {
            int i = (int)threadIdx.x + k * ATH;
            if (i < tn) {
                int dl = (m[k].x >> 20) & (NPB - 1);
                int r = atomicAdd(&cnt2[dl], 1);
                csr[offs[dl] + r] = make_int2(m[k].x & 0xFFFFF, m[k].y);
            }
        }
        if (threadIdx.x < NPB) cnt[threadIdx.x] = 0;
        deg += (float)myc;
        __syncthreads();

        int mybase = offs[g];
        #pragma unroll 4
        for (int s = 0; s < myc; ++s) {
            int2 c = csr[mybase + s];
            const float4* hr = reinterpret_cast<const float4*>(
                h + (size_t)c.x * D_NODE) + 2 * jg;
            float4 h0 = hr[0], h1 = hr[1];
            float4 ev = e4[(size_t)c.y * 4 + jg];
            ha0.x += h0.x; ha0.y += h0.y; ha0.z += h0.z; ha0.w += h0.w;
            ha1.x += h1.x; ha1.y += h1.y; ha1.z += h1.z; ha1.w += h1.w;
            ea.x  += ev.x; ea.y  += ev.y; ea.z  += ev.z; ea.w  += ev.w;
        }
        if (threadIdx.x < NPB) cnt2[threadIdx.x] = 0;
        __syncthreads();
    }

    float (*mrow)[D_IN + 1] = reinterpret_cast<float (*)[D_IN + 1]>(csr);

    int node = blockIdx.x * NPB + g;
    if (node < n_nodes) {
        float inv = 1.f / (deg + 1.f);
        const float4* hs = reinterpret_cast<const float4*>(
            h + (size_t)node * D_NODE) + 2 * jg;
        float4 s0 = hs[0], s1 = hs[1];
        mrow[g][8 * jg + 0] = (ha0.x + s0.x) * inv;
        mrow[g][8 * jg + 1] = (ha0.y + s0.y) * inv;
        mrow[g][8 * jg + 2] = (ha0.z + s0.z) * inv;
        mrow[g][8 * jg + 3] = (ha0.w + s0.w) * inv;
        mrow[g][8 * jg + 4] = (ha1.x + s1.x) * inv;
        mrow[g][8 * jg + 5] = (ha1.y + s1.y) * inv;
        mrow[g][8 * jg + 6] = (ha1.z + s1.z) * inv;
        mrow[g][8 * jg + 7] = (ha1.w + s1.w) * inv;
        mrow[g][D_NODE + 4 * jg + 0] = ea.x * inv;
        mrow[g][D_NODE + 4 * jg + 1] = ea.y * inv;
        mrow[g][D_NODE + 4 * jg + 2] = ea.z * inv;
        mrow[g][D_NODE + 4 * jg + 3] = ea.w * inv;
    }
    __syncthreads();
    if (node >= n_nodes) return;

    const float* row = mrow[g];
    float a[8];
    #pragma unroll
    for (int q = 0; q < 8; ++q) a[q] = bs[jg * 8 + q];
    #pragma unroll
    for (int k = 0; k < D_IN; ++k) {
        float mk = row[k];
        const float* w = Ws + k * D_OUT + jg * 8;
        #pragma unroll
        for (int q = 0; q < 8; ++q) a[q] += mk * w[q];
    }
    float sq = 0.f;
    #pragma unroll
    for (int q = 0; q < 8; ++q) sq += a[q] * a[q];
    sq += __shfl_xor(sq, 1);
    sq += __shfl_xor(sq, 2);
    float r = rsqrtf(fmaxf(sq, L2_EPS));
    float4* o4 = reinterpret_cast<float4*>(out + (size_t)node * D_OUT) + 2 * jg;
    o4[0] = make_float4(a[0] * r, a[1] * r, a[2] * r, a[3] * r);
    o4[1] = make_float4(a[4] * r, a[5] * r, a[6] * r, a[7] * r);
}

// ===========================================================================
// Fallback path (round-1, verified): global f32 atomics + per-node pass.
// ===========================================================================
__global__ __launch_bounds__(256) void scatter_kernel(
    const float* __restrict__ h, const float* __restrict__ e,
    const int* __restrict__ src, const int* __restrict__ dst,
    float* __restrict__ agg, float* __restrict__ deg, int n_edges)
{
    int tid  = blockIdx.x * blockDim.x + threadIdx.x;
    int edge = tid >> 4;
    int c    = tid & 15;
    if (edge >= n_edges) return;
    int s = src[edge], d = dst[edge];
    float v0 = h[(size_t)s * D_NODE + c];
    float v1 = h[(size_t)s * D_NODE + 16 + c];
    float v2 = e[(size_t)edge * D_EDGE + c];
    float* row = agg + (size_t)d * D_IN;
    atomicAdd(row + c, v0);
    atomicAdd(row + 16 + c, v1);
    atomicAdd(row + 32 + c, v2);
    if (c == 0) atomicAdd(deg + d, 1.0f);
}

__global__ __launch_bounds__(256) void node_kernel(
    const float* __restrict__ h, const float* __restrict__ W, const float* __restrict__ b,
    const float* __restrict__ agg, const float* __restrict__ deg,
    float* __restrict__ out, int n_nodes)
{
    __shared__ float Ws[D_IN * D_OUT];
    __shared__ float bs[D_OUT];
    for (int i = threadIdx.x; i < D_IN * D_OUT; i += blockDim.x) Ws[i] = W[i];
    if (threadIdx.x < D_OUT) bs[threadIdx.x] = b[threadIdx.x];
    __syncthreads();
    int node = blockIdx.x * blockDim.x + threadIdx.x;
    if (node >= n_nodes) return;
    const float4* h4 = reinterpret_cast<const float4*>(h + (size_t)node * D_NODE);
    const float4* a4 = reinterpret_cast<const float4*>(agg + (size_t)node * D_IN);
    float inv = 1.0f / (deg[node] + 1.0f);
    float m[D_IN];
    #pragma unroll
    for (int k = 0; k < D_NODE / 4; ++k) {
        float4 hv = h4[k]; float4 av = a4[k];
        m[4*k+0] = (hv.x + av.x) * inv; m[4*k+1] = (hv.y + av.y) * inv;
        m[4*k+2] = (hv.z + av.z) * inv; m[4*k+3] = (hv.w + av.w) * inv;
    }
    #pragma unroll
    for (int k = D_NODE / 4; k < D_IN / 4; ++k) {
        float4 av = a4[k];
        m[4*k+0] = av.x * inv; m[4*k+1] = av.y * inv;
        m[4*k+2] = av.z * inv; m[4*k+3] = av.w * inv;
    }
    float acc[D_OUT];
    #pragma unroll
    for (int j = 0; j < D_OUT; ++j) acc[j] = bs[j];
    #pragma unroll
    for (int k = 0; k < D_IN; ++k) {
        float mk = m[k];
        #pragma unroll
        for (int j = 0; j < D_OUT; ++j) acc[j] += mk * Ws[k * D_OUT + j];
    }
    float sq = 0.0f;
    #pragma unroll
    for (int j = 0; j < D_OUT; ++j) sq += acc[j] * acc[j];
    float r = rsqrtf(fmaxf(sq, L2_EPS));
    float4* o4 = reinterpret_cast<float4*>(out + (size_t)node * D_OUT);
    #pragma unroll
    for (int j = 0; j < D_OUT / 4; ++j) {
        float4 v;
        v.x = acc[4*j+0] * r; v.y = acc[4*j+1] * r;
        v.z = acc[4*j+2] * r; v.w = acc[4*j+3] * r;
        o4[j] = v;
    }
}

extern "C" void kernel_launch(void* const* d_in, const int* in_sizes, int n_in,
                              void* d_out, int out_size, void* d_ws, size_t ws_size,
                              hipStream_t stream) {
    const float* h   = (const float*)d_in[0];
    const float* e   = (const float*)d_in[1];
    const float* W   = (const float*)d_in[2];
    const float* b   = (const float*)d_in[3];
    const int*   src = (const int*)d_in[4];
    const int*   dst = (const int*)d_in[5];
    float* out = (float*)d_out;

    const int n_nodes = in_sizes[0] / D_NODE;
    const int n_edges = in_sizes[4];

    const int nb = (n_nodes + NPB - 1) / NPB;
    const int nc = (n_edges + CH - 1) / CH;

    bool ok_common = (nb <= MAX_NB) && (n_nodes < (1 << 20)) && (n_edges > 0);

    // tier A layout (int units): cursor[nb] | ovf_cnt[1] | pad4 | slab int2[nb*CAPB] | pad4 | ovf int4[E]
    size_t a_cursor = 0;
    size_t a_ovfc   = a_cursor + nb;
    size_t a_slab   = (a_ovfc + 1 + 3) & ~(size_t)3;
    size_t a_ovf    = (a_slab + (size_t)nb * CAPB * 2 + 3) & ~(size_t)3;
    size_t need_A   = (a_ovf + (size_t)n_edges * 4) * sizeof(int);

    // tier B layout (int units): cnt[nb] | offsets[nb+1] | cursor[nb] | pad | meta2 int2[E]
    size_t b_cnt     = 0;
    size_t b_offsets = b_cnt + nb;
    size_t b_cursor  = b_offsets + nb + 1;
    size_t b_meta2   = (b_cursor + (size_t)nb + 1) & ~(size_t)1;
    size_t need_B    = (b_meta2 + (size_t)n_edges * 2) * sizeof(int);

    if (ok_common && need_A <= ws_size) {
        int* ws_i    = (int*)d_ws;
        int* cursor  = ws_i + a_cursor;
        int* ovfc    = ws_i + a_ovfc;
        int2* slab   = (int2*)(ws_i + a_slab);
        int4* ovf    = (int4*)(ws_i + a_ovf);

        hipMemsetAsync(cursor, 0, (size_t)(nb + 1) * sizeof(int), stream);
        k_scatter_c<<<nc, CTH, (size_t)3 * nb * sizeof(int), stream>>>(
            dst, src, cursor, ovfc, slab, ovf, n_edges, nb);
        k_accum_c<<<nb, ATH, 0, stream>>>(
            h, (const float4*)e, W, b, cursor, ovfc, slab, ovf, out, n_nodes);
    } else if (ok_common && need_B <= ws_size) {
        int* ws_i    = (int*)d_ws;
        int* cnt     = ws_i + b_cnt;
        int* offsets = ws_i + b_offsets;
        int* cursor  = ws_i + b_cursor;
        int2* meta2  = (int2*)(ws_i + b_meta2);

        hipMemsetAsync(cnt, 0, (size_t)nb * sizeof(int), stream);
        k_count<<<nc, CTH, (size_t)nb * sizeof(int), stream>>>(
            dst, cnt, n_edges, nb);
        k_offs2<<<1, 1024, 0, stream>>>(cnt, offsets, cursor, nb);
        k_scatter_g<<<nc, CTH, (size_t)3 * nb * sizeof(int), stream>>>(
            dst, src, cursor, meta2, n_edges, nb);
        k_accum_g<<<nb, ATH, 0, stream>>>(
            h, (const float4*)e, W, b, offsets, meta2, out, n_nodes);
    } else {
        float* agg = (float*)d_ws;
        float* deg = agg + (size_t)n_nodes * D_IN;
        hipMemsetAsync(d_ws, 0, (size_t)n_nodes * (D_IN + 1) * sizeof(float), stream);
        long long threads = (long long)n_edges * 16;
        scatter_kernel<<<(int)((threads + 255) / 256), 256, 0, stream>>>(h, e, src, dst, agg, deg, n_edges);
        node_kernel<<<(n_nodes + 255) / 256, 256, 0, stream>>>(h, W, b, agg, deg, out, n_nodes);
    }
}